// Round 2
// baseline (20.045 us; speedup 1.0000x reference)
//
#include <hip/hip_runtime.h>

// out[b, 3p+r, 3q+c] = 0                  if p == q
//                    = ±H[b, 3p+r, 3q+c]  otherwise,
// sign = -1 iff (u_s[b, max(p,q)] < 0) && ((r==2) XOR (c==2))
//
// Thread layout: blockDim=(128,4). Each thread owns 12 consecutive columns
// of one row = 4 whole 3x3 column-blocks (q = 4t..4t+3), so its u_s lookups
// are ONE contiguous float4 (plus the block-uniform u_s[p]). 3 float4 H
// loads issue back-to-back for ILP; 3 float4 stores.
__global__ __launch_bounds__(512)
void jflip_kernel(const float* __restrict__ H,
                  const float* __restrict__ u_s,
                  float* __restrict__ out,
                  int N, int D) {
    const int b = blockIdx.y;
    const int R = blockIdx.x * 4 + threadIdx.y;   // output row
    const int p = R / 3;                          // row 3x3-block index
    const int r = R - 3 * p;
    const bool r2 = (r == 2);

    const int t    = threadIdx.x;   // 0..127
    const int q0   = t * 4;         // first column-block owned
    const int col0 = t * 12;        // first column (12 ≡ 0 mod 4 -> 16B aligned)

    const float* usb = u_s + (long long)b * N;
    const long long off = ((long long)b * D + R) * D + col0;

    // Issue all loads up front (ILP).
    const float4 h0 = *reinterpret_cast<const float4*>(H + off);
    const float4 h1 = *reinterpret_cast<const float4*>(H + off + 4);
    const float4 h2 = *reinterpret_cast<const float4*>(H + off + 8);
    const float4 u4 = *reinterpret_cast<const float4*>(usb + q0);
    const float  up = usb[p];       // wave-uniform (same for whole row)

    const float hv[12] = {h0.x, h0.y, h0.z, h0.w,
                          h1.x, h1.y, h1.z, h1.w,
                          h2.x, h2.y, h2.z, h2.w};
    const float uv[4]  = {u4.x, u4.y, u4.z, u4.w};
    float ov[12];

#pragma unroll
    for (int j = 0; j < 4; ++j) {
        const int q = q0 + j;
        const bool diag = (q == p);
        const bool ind  = ((q > p) ? uv[j] : up) < 0.0f;
#pragma unroll
        for (int c = 0; c < 3; ++c) {
            const int m = 3 * j + c;
            const bool flip = ind && (r2 != (c == 2));
            const float v = flip ? -hv[m] : hv[m];
            ov[m] = diag ? 0.0f : v;
        }
    }

    *reinterpret_cast<float4*>(out + off)     = make_float4(ov[0], ov[1], ov[2],  ov[3]);
    *reinterpret_cast<float4*>(out + off + 4) = make_float4(ov[4], ov[5], ov[6],  ov[7]);
    *reinterpret_cast<float4*>(out + off + 8) = make_float4(ov[8], ov[9], ov[10], ov[11]);
}

extern "C" void kernel_launch(void* const* d_in, const int* in_sizes, int n_in,
                              void* d_out, int out_size, void* d_ws, size_t ws_size,
                              hipStream_t stream) {
    const float* H   = (const float*)d_in[0];
    const float* u_s = (const float*)d_in[1];
    float* out = (float*)d_out;

    // in_sizes[0] = B*(3N)^2 = 9*B*N^2, in_sizes[1] = B*N
    const long long nH  = (long long)in_sizes[0];
    const long long nUs = (long long)in_sizes[1];
    const int N = (int)(nH / (9LL * nUs));   // 512
    const int B = (int)(nUs / N);            // 4
    const int D = 3 * N;                     // 1536

    dim3 block(128, 4);                      // 512 threads: 4 rows x 128 col-chunks
    dim3 grid((unsigned)(D / 4), (unsigned)B);

    jflip_kernel<<<grid, block, 0, stream>>>(H, u_s, out, N, D);
}

// Round 3
// 16.993 us; speedup vs baseline: 1.1796x; 1.1796x over previous
//
#include <hip/hip_runtime.h>

// out[b, 3p+r, 3q+c] = 0                  if p == q
//                    = ±H[b, 3p+r, 3q+c]  otherwise,
// sign = -1 iff (u_s[b, max(p,q)] < 0) && ((r==2) XOR (c==2))
//
// Geometry: block = 384 threads, each thread owns ONE float4 column slot
// (C0 = 4*tid, perfectly coalesced: each wave instruction = contiguous
// 1024 B) and loops over 8 consecutive rows. The 8 loads are issued
// back-to-back -> 8 outstanding VMEM ops per thread to hide HBM latency.
// u_s signs for the thread's 2 column-blocks are loaded once and reused
// across all 8 rows; u_s[p] is block-uniform per row -> scalar load.
__global__ __launch_bounds__(384)
void jflip_kernel(const float* __restrict__ H,
                  const float* __restrict__ u_s,
                  float* __restrict__ out,
                  int N, int D) {
    const int b  = blockIdx.y;
    const int R0 = blockIdx.x * 8;        // first of 8 rows
    const int C0 = threadIdx.x * 4;       // this thread's 4 columns

    const float* usb = u_s + (long long)b * N;

    // Per-column metadata, reused for all 8 rows.
    int  qk[4];  bool c2k[4];  bool iqk[4];
    {
        const int q0 = C0 / 3;
        const int q1 = (C0 + 3) / 3;
        const bool i0 = usb[q0] < 0.0f;
        const bool i1 = usb[q1] < 0.0f;
#pragma unroll
        for (int k = 0; k < 4; ++k) {
            const int C = C0 + k;
            const int q = C / 3;
            qk[k]  = q;
            c2k[k] = (C - 3 * q) == 2;
            iqk[k] = (q == q0) ? i0 : i1;
        }
    }

    const long long base = ((long long)b * D + R0) * D + C0;

    // Issue all 8 row-loads up front (ILP / latency hiding).
    float4 h[8];
#pragma unroll
    for (int i = 0; i < 8; ++i)
        h[i] = *reinterpret_cast<const float4*>(H + base + (long long)i * D);

#pragma unroll
    for (int i = 0; i < 8; ++i) {
        const int R = R0 + i;
        const int p = R / 3;
        const bool r2   = (R - 3 * p) == 2;
        const bool indp = usb[p] < 0.0f;   // block-uniform -> s_load

        const float v[4] = {h[i].x, h[i].y, h[i].z, h[i].w};
        float o[4];
#pragma unroll
        for (int k = 0; k < 4; ++k) {
            const int q = qk[k];
            const bool ind  = (q > p) ? iqk[k] : indp;
            const bool flip = ind && (r2 != c2k[k]);
            const float val = flip ? -v[k] : v[k];
            o[k] = (q == p) ? 0.0f : val;
        }
        *reinterpret_cast<float4*>(out + base + (long long)i * D) =
            make_float4(o[0], o[1], o[2], o[3]);
    }
}

extern "C" void kernel_launch(void* const* d_in, const int* in_sizes, int n_in,
                              void* d_out, int out_size, void* d_ws, size_t ws_size,
                              hipStream_t stream) {
    const float* H   = (const float*)d_in[0];
    const float* u_s = (const float*)d_in[1];
    float* out = (float*)d_out;

    // in_sizes[0] = B*(3N)^2 = 9*B*N^2, in_sizes[1] = B*N
    const long long nH  = (long long)in_sizes[0];
    const long long nUs = (long long)in_sizes[1];
    const int N = (int)(nH / (9LL * nUs));   // 512
    const int B = (int)(nUs / N);            // 4
    const int D = 3 * N;                     // 1536

    dim3 block(384);                          // one float4 column slot each
    dim3 grid((unsigned)(D / 8), (unsigned)B); // 8 rows per block

    jflip_kernel<<<grid, block, 0, stream>>>(H, u_s, out, N, D);
}